// Round 1
// baseline (108.913 us; speedup 1.0000x reference)
//
#include <hip/hip_runtime.h>
#include <math.h>

#define NHEADS 8
#define KD 16
#define EMBED 128
#define BATCH 32
#define NSEQ 16384
#define NCHUNK 64
#define CHUNK (NSEQ / NCHUNK)   // 256 rows per chunk
#define PART_STRIDE 18          // m, l, acc[16]

// Kernel 1: per-(batch, chunk) online-softmax partials over all 8 heads.
// Each wave reads whole 128-float rows: lane l covers dims [2l, 2l+1],
// head = lane>>3 (8 lanes per head, 16 dims per head).
__global__ __launch_bounds__(256) void attn_partial(
    const float* __restrict__ q,
    const float* __restrict__ K,
    const float* __restrict__ V,
    const float* __restrict__ mask,
    float* __restrict__ part)
{
    const int b    = blockIdx.x >> 6;      // NCHUNK == 64
    const int c    = blockIdx.x & 63;
    const int wave = threadIdx.x >> 6;
    const int lane = threadIdx.x & 63;
    const int head = lane >> 3;
    const int g    = lane & 7;             // position within head group

    const float2 q2 = *(const float2*)&q[b * EMBED + 2 * lane];

    float m = -INFINITY;
    float lsum = 0.f;
    float accx = 0.f, accy = 0.f;

    const size_t rowbase = (size_t)b * NSEQ;
    const int r0 = c * CHUNK;

    #pragma unroll 4
    for (int r = r0 + wave; r < r0 + CHUNK; r += 4) {
        const size_t off = (rowbase + r) * EMBED + 2 * lane;
        const float2 k2 = *(const float2*)&K[off];
        float p = q2.x * k2.x + q2.y * k2.y;
        p += __shfl_xor(p, 1);
        p += __shfl_xor(p, 2);
        p += __shfl_xor(p, 4);
        const float s  = p * 0.25f + mask[rowbase + r];   // scale = 1/sqrt(16)
        const float mn = fmaxf(m, s);
        const float corr = __expf(m - mn);
        const float w    = __expf(s - mn);
        const float2 v2 = *(const float2*)&V[off];
        lsum = lsum * corr + w;
        accx = accx * corr + w * v2.x;
        accy = accy * corr + w * v2.y;
        m = mn;
    }

    // Combine the 4 waves' partials via LDS.
    __shared__ float lds[4][NHEADS][PART_STRIDE];
    lds[wave][head][2 + 2 * g]     = accx;
    lds[wave][head][2 + 2 * g + 1] = accy;
    if (g == 0) {
        lds[wave][head][0] = m;
        lds[wave][head][1] = lsum;
    }
    __syncthreads();

    const int t = threadIdx.x;
    if (t < EMBED) {
        const int h = t >> 4;
        const int d = t & 15;
        float M = -INFINITY;
        #pragma unroll
        for (int w = 0; w < 4; ++w) M = fmaxf(M, lds[w][h][0]);
        float L = 0.f, A = 0.f;
        #pragma unroll
        for (int w = 0; w < 4; ++w) {
            const float e = __expf(lds[w][h][0] - M);
            L += lds[w][h][1] * e;
            A += lds[w][h][2 + d] * e;
        }
        float* p = &part[((size_t)(b * NCHUNK + c) * NHEADS + h) * PART_STRIDE];
        p[2 + d] = A;
        if (d == 0) { p[0] = M; p[1] = L; }
    }
}

// Kernel 2: merge chunk partials, normalize, apply W_out projection.
__global__ __launch_bounds__(128) void attn_finish(
    const float* __restrict__ part,
    const float* __restrict__ Wout,
    float* __restrict__ out)
{
    const int b = blockIdx.x;
    const int t = threadIdx.x;
    const int h = t >> 4;
    const int d = t & 15;

    __shared__ float heads[EMBED];

    float M = -INFINITY, L = 0.f, A = 0.f;
    for (int c = 0; c < NCHUNK; ++c) {
        const float* p = &part[((size_t)(b * NCHUNK + c) * NHEADS + h) * PART_STRIDE];
        const float mc = p[0];
        const float Mn = fmaxf(M, mc);
        const float eM = __expf(M - Mn);
        const float ec = __expf(mc - Mn);
        L = L * eM + p[1] * ec;
        A = A * eM + p[2 + d] * ec;
        M = Mn;
    }
    heads[t] = A / L;
    __syncthreads();

    float o = 0.f;
    #pragma unroll 8
    for (int dd = 0; dd < EMBED; ++dd)
        o += heads[dd] * Wout[dd * EMBED + t];
    out[b * EMBED + t] = o;
}

extern "C" void kernel_launch(void* const* d_in, const int* in_sizes, int n_in,
                              void* d_out, int out_size, void* d_ws, size_t ws_size,
                              hipStream_t stream) {
    const float* q    = (const float*)d_in[0];
    const float* K    = (const float*)d_in[1];
    const float* V    = (const float*)d_in[2];
    const float* mask = (const float*)d_in[3];
    const float* Wout = (const float*)d_in[4];
    float* out  = (float*)d_out;
    float* part = (float*)d_ws;   // BATCH*NCHUNK*NHEADS*18 floats ≈ 1.13 MB

    attn_partial<<<BATCH * NCHUNK, 256, 0, stream>>>(q, K, V, mask, part);
    attn_finish<<<BATCH, 128, 0, stream>>>(part, Wout, out);
}